// Round 2
// baseline (810.314 us; speedup 1.0000x reference)
//
#include <hip/hip_runtime.h>
#include <hip/hip_bf16.h>
#include <stdint.h>

typedef __bf16 bf16;
typedef __bf16 bf16x8 __attribute__((ext_vector_type(8)));
typedef __bf16 bf16x4 __attribute__((ext_vector_type(4)));
typedef float  f32x4  __attribute__((ext_vector_type(4)));

#define GLOAD16(gsrc, ldst)                                                        \
  __builtin_amdgcn_global_load_lds(                                               \
      (const __attribute__((address_space(1))) void*)(gsrc),                      \
      (__attribute__((address_space(3))) void*)(ldst), 16, 0, 0)

__device__ __forceinline__ float gelu_f(float v) {
  return 0.5f * v * (1.0f + erff(v * 0.70710678118654752f));
}

// ---------------- transpose + cast: W[K,N] f32 -> Wt[N,K] bf16 ----------------
__global__ __launch_bounds__(256) void transpose_cast_k(
    const float* __restrict__ W, bf16* __restrict__ Wt, int K, int N) {
  __shared__ float tile[32][33];
  const int n0 = blockIdx.x * 32, k0 = blockIdx.y * 32;
  const int tx = threadIdx.x & 31, ty = threadIdx.x >> 5;
#pragma unroll
  for (int i = ty; i < 32; i += 8)
    tile[i][tx] = W[(size_t)(k0 + i) * N + n0 + tx];
  __syncthreads();
#pragma unroll
  for (int i = ty; i < 32; i += 8)
    Wt[(size_t)(n0 + i) * K + k0 + tx] = (bf16)tile[tx][i];
}

// ---------------- LayerNorm: f32 [T,768] -> bf16 [T,768] ----------------
__global__ __launch_bounds__(256) void ln_k(
    const float* __restrict__ x, const float* __restrict__ g,
    const float* __restrict__ b, bf16* __restrict__ out) {
  const int token = blockIdx.x * 4 + (threadIdx.x >> 6);
  const int lane  = threadIdx.x & 63;
  const float4* xp = (const float4*)(x + (size_t)token * 768);
  float4 v[3];
  float s = 0.f, ss = 0.f;
#pragma unroll
  for (int j = 0; j < 3; j++) {
    v[j] = xp[lane + j * 64];
    s  += v[j].x + v[j].y + v[j].z + v[j].w;
    ss += v[j].x * v[j].x + v[j].y * v[j].y + v[j].z * v[j].z + v[j].w * v[j].w;
  }
#pragma unroll
  for (int o = 32; o > 0; o >>= 1) { s += __shfl_xor(s, o); ss += __shfl_xor(ss, o); }
  const float mu  = s * (1.f / 768.f);
  const float var = ss * (1.f / 768.f) - mu * mu;
  const float r   = rsqrtf(var + 1e-5f);
#pragma unroll
  for (int j = 0; j < 3; j++) {
    const int c0 = (lane + j * 64) * 4;
    bf16x4 o4;
    o4[0] = (bf16)((v[j].x - mu) * r * g[c0 + 0] + b[c0 + 0]);
    o4[1] = (bf16)((v[j].y - mu) * r * g[c0 + 1] + b[c0 + 1]);
    o4[2] = (bf16)((v[j].z - mu) * r * g[c0 + 2] + b[c0 + 2]);
    o4[3] = (bf16)((v[j].w - mu) * r * g[c0 + 3] + b[c0 + 3]);
    *(bf16x4*)(out + (size_t)token * 768 + c0) = o4;
  }
}

// ---------------- generic GEMM: C[M,N] = A[M,K] @ Bt[N,K]^T ----------------
// EPI 0: out bf16 = acc + bias
// EPI 1: out bf16 = gelu(acc + bias)
// EPI 2: out f32  = acc + bias + res   (res has same layout/ld as out)
template <int EPI>
__global__ __launch_bounds__(256) void gemm_bt_k(
    const bf16* __restrict__ A, int lda,
    const bf16* __restrict__ Bt, int ldb,
    const float* __restrict__ bias,
    const float* __restrict__ res,
    void* __restrict__ outp, int ldc, int K) {
  __shared__ __align__(16) bf16 As[128 * 64];
  __shared__ __align__(16) bf16 Bs[128 * 64];
  const int t = threadIdx.x, wave = t >> 6, lane = t & 63;
  const int row0 = blockIdx.y * 128, col0 = blockIdx.x * 128;
  const int wm = wave >> 1, wn = wave & 1;
  const int sr = t >> 3, sc = (t & 7) * 8;

  f32x4 acc[4][4];
#pragma unroll
  for (int m = 0; m < 4; m++)
#pragma unroll
    for (int n = 0; n < 4; n++) acc[m][n] = f32x4{0.f, 0.f, 0.f, 0.f};

  const bf16* a_src = A + (size_t)(row0 + sr) * lda + sc;
  const bf16* b_src = Bt + (size_t)(col0 + sr) * ldb + sc;
  bf16* a_dst = As + wave * 512;
  bf16* b_dst = Bs + wave * 512;

  for (int k0 = 0; k0 < K; k0 += 64) {
#pragma unroll
    for (int i = 0; i < 4; i++) {
      GLOAD16(a_src + (size_t)i * 32 * lda + k0, a_dst + i * 2048);
      GLOAD16(b_src + (size_t)i * 32 * ldb + k0, b_dst + i * 2048);
    }
    __syncthreads();
#pragma unroll
    for (int kk = 0; kk < 2; kk++) {
      const int ko = kk * 32 + (lane >> 4) * 8;
      bf16x8 af[4], bfr[4];
#pragma unroll
      for (int m = 0; m < 4; m++)
        af[m] = *(const bf16x8*)(As + (wm * 64 + m * 16 + (lane & 15)) * 64 + ko);
#pragma unroll
      for (int n = 0; n < 4; n++)
        bfr[n] = *(const bf16x8*)(Bs + (wn * 64 + n * 16 + (lane & 15)) * 64 + ko);
#pragma unroll
      for (int m = 0; m < 4; m++)
#pragma unroll
        for (int n = 0; n < 4; n++)
          acc[m][n] = __builtin_amdgcn_mfma_f32_16x16x32_bf16(af[m], bfr[n], acc[m][n], 0, 0, 0);
    }
    __syncthreads();
  }

  const int rbase = row0 + wm * 64 + (lane >> 4) * 4;
  const int cbase = col0 + wn * 64 + (lane & 15);
#pragma unroll
  for (int n = 0; n < 4; n++) {
    const int c = cbase + n * 16;
    const float bv = bias[c];
#pragma unroll
    for (int m = 0; m < 4; m++) {
#pragma unroll
      for (int r = 0; r < 4; r++) {
        const int rr = rbase + m * 16 + r;
        const float vacc = acc[m][n][r] + bv;
        if constexpr (EPI == 0) {
          ((bf16*)outp)[(size_t)rr * ldc + c] = (bf16)vacc;
        } else if constexpr (EPI == 1) {
          ((bf16*)outp)[(size_t)rr * ldc + c] = (bf16)gelu_f(vacc);
        } else {
          ((float*)outp)[(size_t)rr * ldc + c] = vacc + res[(size_t)rr * ldc + c];
        }
      }
    }
  }
}

// ---------------- QK^T: S[bh] = (q @ k^T) * SCALE, f32 into d_out ----------------
__global__ __launch_bounds__(256) void qk_k(const bf16* __restrict__ qkv,
                                            float* __restrict__ attn) {
  __shared__ __align__(16) bf16 Qs[128 * 64];
  __shared__ __align__(16) bf16 Ks[128 * 64];
  const int t = threadIdx.x, wave = t >> 6, lane = t & 63;
  const int bh = blockIdx.z, b = bh / 12, h = bh % 12;
  const bf16* qb = qkv + (size_t)b * 1024 * 2304 + h * 64;
  const bf16* kb = qb + 768;
  float* S = attn + (size_t)bh * 1048576;
  const int row0 = blockIdx.y * 128, col0 = blockIdx.x * 128;
  const int wm = wave >> 1, wn = wave & 1;
  const int sr = t >> 3, sc = (t & 7) * 8;

  f32x4 acc[4][4];
#pragma unroll
  for (int m = 0; m < 4; m++)
#pragma unroll
    for (int n = 0; n < 4; n++) acc[m][n] = f32x4{0.f, 0.f, 0.f, 0.f};

#pragma unroll
  for (int i = 0; i < 4; i++) {
    GLOAD16(qb + (size_t)(row0 + i * 32 + sr) * 2304 + sc, Qs + wave * 512 + i * 2048);
    GLOAD16(kb + (size_t)(col0 + i * 32 + sr) * 2304 + sc, Ks + wave * 512 + i * 2048);
  }
  __syncthreads();
#pragma unroll
  for (int kk = 0; kk < 2; kk++) {
    const int ko = kk * 32 + (lane >> 4) * 8;
    bf16x8 af[4], bfr[4];
#pragma unroll
    for (int m = 0; m < 4; m++)
      af[m] = *(const bf16x8*)(Qs + (wm * 64 + m * 16 + (lane & 15)) * 64 + ko);
#pragma unroll
    for (int n = 0; n < 4; n++)
      bfr[n] = *(const bf16x8*)(Ks + (wn * 64 + n * 16 + (lane & 15)) * 64 + ko);
#pragma unroll
    for (int m = 0; m < 4; m++)
#pragma unroll
      for (int n = 0; n < 4; n++)
        acc[m][n] = __builtin_amdgcn_mfma_f32_16x16x32_bf16(af[m], bfr[n], acc[m][n], 0, 0, 0);
  }

  const int rbase = row0 + wm * 64 + (lane >> 4) * 4;
  const int cbase = col0 + wn * 64 + (lane & 15);
#pragma unroll
  for (int n = 0; n < 4; n++) {
    const int c = cbase + n * 16;
#pragma unroll
    for (int m = 0; m < 4; m++) {
#pragma unroll
      for (int r = 0; r < 4; r++) {
        const int rr = rbase + m * 16 + r;
        S[(size_t)rr * 1024 + c] = acc[m][n][r] * 0.125f;
      }
    }
  }
}

// ---------------- row softmax in place: one wave per 1024-wide row ----------------
__global__ __launch_bounds__(256) void softmax_k(float* __restrict__ attn) {
  const size_t row = (size_t)blockIdx.x * 4 + (threadIdx.x >> 6);
  const int lane = threadIdx.x & 63;
  float4* p = (float4*)(attn + row * 1024);
  float4 v[4];
  float mx = -3.4e38f;
#pragma unroll
  for (int j = 0; j < 4; j++) {
    v[j] = p[lane + j * 64];
    mx = fmaxf(mx, fmaxf(fmaxf(v[j].x, v[j].y), fmaxf(v[j].z, v[j].w)));
  }
#pragma unroll
  for (int o = 32; o > 0; o >>= 1) mx = fmaxf(mx, __shfl_xor(mx, o));
  float s = 0.f;
#pragma unroll
  for (int j = 0; j < 4; j++) {
    v[j].x = expf(v[j].x - mx); v[j].y = expf(v[j].y - mx);
    v[j].z = expf(v[j].z - mx); v[j].w = expf(v[j].w - mx);
    s += v[j].x + v[j].y + v[j].z + v[j].w;
  }
#pragma unroll
  for (int o = 32; o > 0; o >>= 1) s += __shfl_xor(s, o);
  const float inv = 1.f / s;
#pragma unroll
  for (int j = 0; j < 4; j++) {
    v[j].x *= inv; v[j].y *= inv; v[j].z *= inv; v[j].w *= inv;
    p[lane + j * 64] = v[j];
  }
}

// ---------------- V transpose: vT[bh][d][q] <- qkv[b*1024+q][1536+h*64+d] ----------------
__global__ __launch_bounds__(256) void vtrans_k(const bf16* __restrict__ qkv,
                                                bf16* __restrict__ vT) {
  __shared__ bf16 tile[32][33];
  const int bh = blockIdx.z, b = bh / 12, h = bh % 12;
  const int q0 = blockIdx.x * 32, d0 = blockIdx.y * 32;
  const int tx = threadIdx.x & 31, ty = threadIdx.x >> 5;
  const bf16* src = qkv + (size_t)b * 1024 * 2304 + 1536 + h * 64;
#pragma unroll
  for (int i = ty; i < 32; i += 8)
    tile[i][tx] = src[(size_t)(q0 + i) * 2304 + d0 + tx];
  __syncthreads();
  bf16* dst = vT + (size_t)bh * 65536;
#pragma unroll
  for (int i = ty; i < 32; i += 8)
    dst[(size_t)(d0 + i) * 1024 + q0 + tx] = tile[tx][i];
}

// ---------------- PV: out_bh[1024,64] = P[1024,1024] @ V ; out bf16 [T,768] ----------------
__global__ __launch_bounds__(256) void pv_k(const float* __restrict__ attn,
                                            const bf16* __restrict__ vT,
                                            bf16* __restrict__ outp) {
  const int bh = blockIdx.z, b = bh / 12, h = bh % 12;
  const float* P = attn + (size_t)bh * 1048576;
  const bf16* Vt = vT + (size_t)bh * 65536;
  const int wave = threadIdx.x >> 6, lane = threadIdx.x & 63;
  const int row0 = blockIdx.x * 128 + wave * 32;

  f32x4 acc[2][4];
#pragma unroll
  for (int m = 0; m < 2; m++)
#pragma unroll
    for (int n = 0; n < 4; n++) acc[m][n] = f32x4{0.f, 0.f, 0.f, 0.f};

  for (int k0 = 0; k0 < 1024; k0 += 32) {
    const int ko = k0 + (lane >> 4) * 8;
    bf16x8 af[2];
#pragma unroll
    for (int m = 0; m < 2; m++) {
      const float* ap = P + (size_t)(row0 + m * 16 + (lane & 15)) * 1024 + ko;
      const float4 lo = *(const float4*)ap;
      const float4 hi = *(const float4*)(ap + 4);
      bf16x8 a;
      a[0] = (bf16)lo.x; a[1] = (bf16)lo.y; a[2] = (bf16)lo.z; a[3] = (bf16)lo.w;
      a[4] = (bf16)hi.x; a[5] = (bf16)hi.y; a[6] = (bf16)hi.z; a[7] = (bf16)hi.w;
      af[m] = a;
    }
    bf16x8 bfr[4];
#pragma unroll
    for (int n = 0; n < 4; n++)
      bfr[n] = *(const bf16x8*)(Vt + (size_t)(n * 16 + (lane & 15)) * 1024 + ko);
#pragma unroll
    for (int m = 0; m < 2; m++)
#pragma unroll
      for (int n = 0; n < 4; n++)
        acc[m][n] = __builtin_amdgcn_mfma_f32_16x16x32_bf16(af[m], bfr[n], acc[m][n], 0, 0, 0);
  }

#pragma unroll
  for (int m = 0; m < 2; m++) {
#pragma unroll
    for (int n = 0; n < 4; n++) {
#pragma unroll
      for (int r = 0; r < 4; r++) {
        const int rr = row0 + m * 16 + (lane >> 4) * 4 + r;
        const int c  = n * 16 + (lane & 15);
        outp[(size_t)(b * 1024 + rr) * 768 + h * 64 + c] = (bf16)acc[m][n][r];
      }
    }
  }
}

// ---------------- blend: xa = 0.5*xa + 0.5*xb ----------------
__global__ __launch_bounds__(256) void blend_k(float* __restrict__ xa,
                                               const float* __restrict__ xb, int n4) {
  const int i = blockIdx.x * 256 + threadIdx.x;
  if (i < n4) {
    float4 a = ((float4*)xa)[i];
    const float4 c = ((const float4*)xb)[i];
    a.x = 0.5f * (a.x + c.x); a.y = 0.5f * (a.y + c.y);
    a.z = 0.5f * (a.z + c.z); a.w = 0.5f * (a.w + c.w);
    ((float4*)xa)[i] = a;
  }
}

// ---------------- host ----------------
extern "C" void kernel_launch(void* const* d_in, const int* in_sizes, int n_in,
                              void* d_out, int out_size, void* d_ws, size_t ws_size,
                              hipStream_t stream) {
  (void)in_sizes; (void)n_in; (void)out_size; (void)ws_size;
  const float* x = (const float*)d_in[0];
#define IN(d, i) ((const float*)d_in[1 + (d) * 12 + (i)])
  float* outF = (float*)d_out;
  float* attnp[2] = {outF + 3145728, outF + 3145728 + 50331648};

  char* p = (char*)d_ws;
  auto alloc = [&](size_t bytes) { void* r = p; p += bytes; return r; };
  bf16 *qkv_wt[2], *proj_wt[2], *w1t[2], *w2t[2];
  for (int d = 0; d < 2; d++) {
    qkv_wt[d]  = (bf16*)alloc((size_t)2304 * 768 * 2);
    proj_wt[d] = (bf16*)alloc((size_t)768 * 768 * 2);
    w1t[d]     = (bf16*)alloc((size_t)3072 * 768 * 2);
    w2t[d]     = (bf16*)alloc((size_t)768 * 3072 * 2);
  }
  bf16*  hbuf = (bf16*)alloc((size_t)4096 * 768 * 2);
  bf16*  qkvb = (bf16*)alloc((size_t)4096 * 2304 * 2);
  bf16*  vT   = (bf16*)alloc((size_t)48 * 64 * 1024 * 2);
  bf16*  aout = (bf16*)alloc((size_t)4096 * 768 * 2);
  bf16*  hid  = (bf16*)alloc((size_t)4096 * 3072 * 2);
  float* xa   = (float*)alloc((size_t)4096 * 768 * 4);
  float* xb   = (float*)alloc((size_t)4096 * 768 * 4);

  for (int d = 0; d < 2; d++) {
    transpose_cast_k<<<dim3(72, 24), 256, 0, stream>>>(IN(d, 0), qkv_wt[d], 768, 2304);
    transpose_cast_k<<<dim3(24, 24), 256, 0, stream>>>(IN(d, 2), proj_wt[d], 768, 768);
    transpose_cast_k<<<dim3(96, 24), 256, 0, stream>>>(IN(d, 8), w1t[d], 768, 3072);
    transpose_cast_k<<<dim3(24, 96), 256, 0, stream>>>(IN(d, 10), w2t[d], 3072, 768);
  }

  auto attention = [&](int d, const float* xin, float* xout) {
    ln_k<<<1024, 256, 0, stream>>>(xin, IN(d, 4), IN(d, 5), hbuf);
    gemm_bt_k<0><<<dim3(18, 32), 256, 0, stream>>>(hbuf, 768, qkv_wt[d], 768, IN(d, 1),
                                                   nullptr, qkvb, 2304, 768);
    vtrans_k<<<dim3(32, 2, 48), 256, 0, stream>>>(qkvb, vT);
    qk_k<<<dim3(8, 8, 48), 256, 0, stream>>>(qkvb, attnp[d]);
    softmax_k<<<12288, 256, 0, stream>>>(attnp[d]);
    pv_k<<<dim3(8, 1, 48), 256, 0, stream>>>(attnp[d], vT, aout);
    gemm_bt_k<2><<<dim3(6, 32), 256, 0, stream>>>(aout, 768, proj_wt[d], 768, IN(d, 3),
                                                  xin, xout, 768, 768);
  };

  // layer 0 attention: xa = x + attn0(LN1_0(x))
  attention(0, x, xa);
  // layer 1 attention: xb = xa + attn1(LN1_1(xa))
  attention(1, xa, xb);
  // layer 1 MLP: xb <- xb + mlp1(LN2_1(xb))   (x_sub)
  ln_k<<<1024, 256, 0, stream>>>(xb, IN(1, 6), IN(1, 7), hbuf);
  gemm_bt_k<1><<<dim3(24, 32), 256, 0, stream>>>(hbuf, 768, w1t[1], 768, IN(1, 9),
                                                 nullptr, hid, 3072, 768);
  gemm_bt_k<2><<<dim3(6, 32), 256, 0, stream>>>(hid, 3072, w2t[1], 3072, IN(1, 11),
                                                xb, xb, 768, 3072);
  // blend: xa <- 0.5*xa + 0.5*xb
  blend_k<<<3072, 256, 0, stream>>>(xa, xb, 786432);
  // layer 0 MLP: out = xa + mlp0(LN2_0(xa))
  ln_k<<<1024, 256, 0, stream>>>(xa, IN(0, 6), IN(0, 7), hbuf);
  gemm_bt_k<1><<<dim3(24, 32), 256, 0, stream>>>(hbuf, 768, w1t[0], 768, IN(0, 9),
                                                 nullptr, hid, 3072, 768);
  gemm_bt_k<2><<<dim3(6, 32), 256, 0, stream>>>(hid, 3072, w2t[0], 3072, IN(0, 11),
                                                xa, outF, 768, 3072);
#undef IN
}

// Round 4
// 593.578 us; speedup vs baseline: 1.3651x; 1.3651x over previous
//
#include <hip/hip_runtime.h>
#include <hip/hip_bf16.h>
#include <stdint.h>

typedef __bf16 bf16;
typedef __bf16 bf16x8 __attribute__((ext_vector_type(8)));
typedef __bf16 bf16x4 __attribute__((ext_vector_type(4)));
typedef float  f32x4  __attribute__((ext_vector_type(4)));

#define GLOAD16(gsrc, ldst)                                                        \
  __builtin_amdgcn_global_load_lds(                                               \
      (const __attribute__((address_space(1))) void*)(gsrc),                      \
      (__attribute__((address_space(3))) void*)(ldst), 16, 0, 0)

__device__ __forceinline__ float gelu_f(float v) {
  return 0.5f * v * (1.0f + erff(v * 0.70710678118654752f));
}

// ---------------- transpose + cast: W[K,N] f32 -> Wt[N,K] bf16 ----------------
__global__ __launch_bounds__(256) void transpose_cast_k(
    const float* __restrict__ W, bf16* __restrict__ Wt, int K, int N) {
  __shared__ float tile[32][33];
  const int n0 = blockIdx.x * 32, k0 = blockIdx.y * 32;
  const int tx = threadIdx.x & 31, ty = threadIdx.x >> 5;
#pragma unroll
  for (int i = ty; i < 32; i += 8)
    tile[i][tx] = W[(size_t)(k0 + i) * N + n0 + tx];
  __syncthreads();
#pragma unroll
  for (int i = ty; i < 32; i += 8)
    Wt[(size_t)(n0 + i) * K + k0 + tx] = (bf16)tile[tx][i];
}

// ---------------- LayerNorm: f32 [T,768] -> bf16 [T,768] ----------------
__global__ __launch_bounds__(256) void ln_k(
    const float* __restrict__ x, const float* __restrict__ g,
    const float* __restrict__ b, bf16* __restrict__ out) {
  const int token = blockIdx.x * 4 + (threadIdx.x >> 6);
  const int lane  = threadIdx.x & 63;
  const float4* xp = (const float4*)(x + (size_t)token * 768);
  float4 v[3];
  float s = 0.f, ss = 0.f;
#pragma unroll
  for (int j = 0; j < 3; j++) {
    v[j] = xp[lane + j * 64];
    s  += v[j].x + v[j].y + v[j].z + v[j].w;
    ss += v[j].x * v[j].x + v[j].y * v[j].y + v[j].z * v[j].z + v[j].w * v[j].w;
  }
#pragma unroll
  for (int o = 32; o > 0; o >>= 1) { s += __shfl_xor(s, o); ss += __shfl_xor(ss, o); }
  const float mu  = s * (1.f / 768.f);
  const float var = ss * (1.f / 768.f) - mu * mu;
  const float r   = rsqrtf(var + 1e-5f);
#pragma unroll
  for (int j = 0; j < 3; j++) {
    const int c0 = (lane + j * 64) * 4;
    bf16x4 o4;
    o4[0] = (bf16)((v[j].x - mu) * r * g[c0 + 0] + b[c0 + 0]);
    o4[1] = (bf16)((v[j].y - mu) * r * g[c0 + 1] + b[c0 + 1]);
    o4[2] = (bf16)((v[j].z - mu) * r * g[c0 + 2] + b[c0 + 2]);
    o4[3] = (bf16)((v[j].w - mu) * r * g[c0 + 3] + b[c0 + 3]);
    *(bf16x4*)(out + (size_t)token * 768 + c0) = o4;
  }
}

// ---------------- generic GEMM: C[M,N] = A[M,K] @ Bt[N,K]^T ----------------
template <int EPI>
__global__ __launch_bounds__(256) void gemm_bt_k(
    const bf16* __restrict__ A, int lda,
    const bf16* __restrict__ Bt, int ldb,
    const float* __restrict__ bias,
    const float* __restrict__ res,
    void* __restrict__ outp, int ldc, int K) {
  __shared__ __align__(16) bf16 As[128 * 64];
  __shared__ __align__(16) bf16 Bs[128 * 64];
  const int t = threadIdx.x, wave = t >> 6, lane = t & 63;
  const int row0 = blockIdx.y * 128, col0 = blockIdx.x * 128;
  const int wm = wave >> 1, wn = wave & 1;
  const int sr = t >> 3, sc = (t & 7) * 8;

  f32x4 acc[4][4];
#pragma unroll
  for (int m = 0; m < 4; m++)
#pragma unroll
    for (int n = 0; n < 4; n++) acc[m][n] = f32x4{0.f, 0.f, 0.f, 0.f};

  const bf16* a_src = A + (size_t)(row0 + sr) * lda + sc;
  const bf16* b_src = Bt + (size_t)(col0 + sr) * ldb + sc;
  bf16* a_dst = As + wave * 512;
  bf16* b_dst = Bs + wave * 512;

  for (int k0 = 0; k0 < K; k0 += 64) {
#pragma unroll
    for (int i = 0; i < 4; i++) {
      GLOAD16(a_src + (size_t)i * 32 * lda + k0, a_dst + i * 2048);
      GLOAD16(b_src + (size_t)i * 32 * ldb + k0, b_dst + i * 2048);
    }
    __syncthreads();
#pragma unroll
    for (int kk = 0; kk < 2; kk++) {
      const int ko = kk * 32 + (lane >> 4) * 8;
      bf16x8 af[4], bfr[4];
#pragma unroll
      for (int m = 0; m < 4; m++)
        af[m] = *(const bf16x8*)(As + (wm * 64 + m * 16 + (lane & 15)) * 64 + ko);
#pragma unroll
      for (int n = 0; n < 4; n++)
        bfr[n] = *(const bf16x8*)(Bs + (wn * 64 + n * 16 + (lane & 15)) * 64 + ko);
#pragma unroll
      for (int m = 0; m < 4; m++)
#pragma unroll
        for (int n = 0; n < 4; n++)
          acc[m][n] = __builtin_amdgcn_mfma_f32_16x16x32_bf16(af[m], bfr[n], acc[m][n], 0, 0, 0);
    }
    __syncthreads();
  }

  const int rbase = row0 + wm * 64 + (lane >> 4) * 4;
  const int cbase = col0 + wn * 64 + (lane & 15);
#pragma unroll
  for (int n = 0; n < 4; n++) {
    const int c = cbase + n * 16;
    const float bv = bias[c];
#pragma unroll
    for (int m = 0; m < 4; m++) {
#pragma unroll
      for (int r = 0; r < 4; r++) {
        const int rr = rbase + m * 16 + r;
        const float vacc = acc[m][n][r] + bv;
        if constexpr (EPI == 0) {
          ((bf16*)outp)[(size_t)rr * ldc + c] = (bf16)vacc;
        } else if constexpr (EPI == 1) {
          ((bf16*)outp)[(size_t)rr * ldc + c] = (bf16)gelu_f(vacc);
        } else {
          ((float*)outp)[(size_t)rr * ldc + c] = vacc + res[(size_t)rr * ldc + c];
        }
      }
    }
  }
}

// ---------------- V transpose: vT[bh][d][q] <- qkv[b*1024+q][1536+h*64+d] ----------------
__global__ __launch_bounds__(256) void vtrans_k(const bf16* __restrict__ qkv,
                                                bf16* __restrict__ vT) {
  __shared__ bf16 tile[32][33];
  const int bh = blockIdx.z, b = bh / 12, h = bh % 12;
  const int q0 = blockIdx.x * 32, d0 = blockIdx.y * 32;
  const int tx = threadIdx.x & 31, ty = threadIdx.x >> 5;
  const bf16* src = qkv + (size_t)b * 1024 * 2304 + 1536 + h * 64;
#pragma unroll
  for (int i = ty; i < 32; i += 8)
    tile[i][tx] = src[(size_t)(q0 + i) * 2304 + d0 + tx];
  __syncthreads();
  bf16* dst = vT + (size_t)bh * 65536;
#pragma unroll
  for (int i = ty; i < 32; i += 8)
    dst[(size_t)(d0 + i) * 1024 + q0 + tx] = tile[tx][i];
}

// ---------------- fused attention: S^T via mfma(K,Q), 2-pass softmax, P write, PV ----
// block = 64 q-rows of one (b,h); 4 waves x 16 q each; kv tiles of 128.
__global__ __launch_bounds__(256) void fattn_k(const bf16* __restrict__ qkv,
                                               const bf16* __restrict__ vT,
                                               float* __restrict__ attn,
                                               bf16* __restrict__ aout) {
  __shared__ __align__(16) bf16 Ks[128 * 64];   // K tile, source-swizzled
  __shared__ __align__(16) bf16 Ps[4 * 16 * 128]; // per-wave P tile, swizzled

  // bh-per-XCD clustering: 768 blocks, xcd = bid%8 owns 6 bh completely.
  const int bid = blockIdx.x;
  const int xcd = bid & 7, within = bid >> 3;      // within: 0..95
  const int bh = xcd * 6 + (within >> 4);
  const int qb = within & 15;
  const int b = bh / 12, h = bh % 12;

  const int t = threadIdx.x, w = t >> 6, lane = t & 63;
  const int g = lane >> 4, l16 = lane & 15;
  const int q0 = qb * 64;

  const bf16* qbp = qkv + (size_t)b * 1024 * 2304 + h * 64;
  const bf16* kbp = qbp + 768;
  const bf16* vt = vT + (size_t)bh * 65536;
  float* Pout = attn + (size_t)bh * 1048576;
  bf16* Pw = Ps + w * 2048;

  // Q B-frags in regs (col q = l16, k = d)
  bf16x8 qf[2];
#pragma unroll
  for (int kk = 0; kk < 2; kk++)
    qf[kk] = *(const bf16x8*)(qbp + (size_t)(q0 + w * 16 + l16) * 2304 + kk * 32 + g * 8);

  const int kvr = t >> 3, sl = t & 7;

  float m_run = -3.0e38f, l_run = 0.f;

  // ---------------- pass 1: online (max, sum) ----------------
  for (int kv0 = 0; kv0 < 1024; kv0 += 128) {
#pragma unroll
    for (int i = 0; i < 4; i++) {
      const int kvl = i * 32 + kvr;
      GLOAD16(kbp + (size_t)(kv0 + kvl) * 2304 + (sl ^ (kvl & 7)) * 8,
              Ks + i * 2048 + t * 8);
    }
    __syncthreads();
    f32x4 st[8];
#pragma unroll
    for (int mk = 0; mk < 8; mk++) st[mk] = f32x4{0.f, 0.f, 0.f, 0.f};
#pragma unroll
    for (int kk = 0; kk < 2; kk++) {
#pragma unroll
      for (int mk = 0; mk < 8; mk++) {
        const int kv = mk * 16 + l16;
        const bf16x8 kf = *(const bf16x8*)(Ks + ((kv * 64 + kk * 32 + g * 8) ^ ((kv & 7) << 3)));
        st[mk] = __builtin_amdgcn_mfma_f32_16x16x32_bf16(kf, qf[kk], st[mk], 0, 0, 0);
      }
    }
    __syncthreads();
    float tm = -3.0e38f;
#pragma unroll
    for (int mk = 0; mk < 8; mk++)
#pragma unroll
      for (int r = 0; r < 4; r++) tm = fmaxf(tm, st[mk][r]);
    tm = fmaxf(tm, __shfl_xor(tm, 16));
    tm = fmaxf(tm, __shfl_xor(tm, 32));
    const float mn = fmaxf(m_run, tm);
    const float ms = mn * 0.125f;
    float sum = 0.f;
#pragma unroll
    for (int mk = 0; mk < 8; mk++)
#pragma unroll
      for (int r = 0; r < 4; r++) sum += __expf(fmaf(st[mk][r], 0.125f, -ms));
    sum += __shfl_xor(sum, 16);
    sum += __shfl_xor(sum, 32);
    l_run = l_run * __expf((m_run - mn) * 0.125f) + sum;
    m_run = mn;
  }

  const float msc = m_run * 0.125f;
  const float invl = 1.f / l_run;

  f32x4 oacc[4];
#pragma unroll
  for (int nd = 0; nd < 4; nd++) oacc[nd] = f32x4{0.f, 0.f, 0.f, 0.f};

  // ---------------- pass 2: recompute S, write P, PV ----------------
  for (int kv0 = 0; kv0 < 1024; kv0 += 128) {
#pragma unroll
    for (int i = 0; i < 4; i++) {
      const int kvl = i * 32 + kvr;
      GLOAD16(kbp + (size_t)(kv0 + kvl) * 2304 + (sl ^ (kvl & 7)) * 8,
              Ks + i * 2048 + t * 8);
    }
    __syncthreads();
    f32x4 st[8];
#pragma unroll
    for (int mk = 0; mk < 8; mk++) st[mk] = f32x4{0.f, 0.f, 0.f, 0.f};
#pragma unroll
    for (int kk = 0; kk < 2; kk++) {
#pragma unroll
      for (int mk = 0; mk < 8; mk++) {
        const int kv = mk * 16 + l16;
        const bf16x8 kf = *(const bf16x8*)(Ks + ((kv * 64 + kk * 32 + g * 8) ^ ((kv & 7) << 3)));
        st[mk] = __builtin_amdgcn_mfma_f32_16x16x32_bf16(kf, qf[kk], st[mk], 0, 0, 0);
      }
    }
    __syncthreads();

    // normalize, write P (f32, nontemporal) + P_lds (bf16, swizzled)
    const int q = q0 + w * 16 + l16;
#pragma unroll
    for (int mk = 0; mk < 8; mk++) {
      f32x4 pv;
      pv[0] = __expf(fmaf(st[mk][0], 0.125f, -msc)) * invl;
      pv[1] = __expf(fmaf(st[mk][1], 0.125f, -msc)) * invl;
      pv[2] = __expf(fmaf(st[mk][2], 0.125f, -msc)) * invl;
      pv[3] = __expf(fmaf(st[mk][3], 0.125f, -msc)) * invl;
      __builtin_nontemporal_store(pv, (f32x4*)(Pout + (size_t)q * 1024 + kv0 + mk * 16 + g * 4));
      bf16x4 pb;
      pb[0] = (bf16)pv[0]; pb[1] = (bf16)pv[1]; pb[2] = (bf16)pv[2]; pb[3] = (bf16)pv[3];
      *(bf16x4*)(Pw + ((l16 * 128 + mk * 16 + g * 4) ^ ((l16 & 7) << 3))) = pb;
    }

    // PV: A = P (rows q, k kv-contig), B = V^T frags from global (L2)
#pragma unroll
    for (int kkv = 0; kkv < 4; kkv++) {
      const bf16x8 pf = *(const bf16x8*)(Pw + ((l16 * 128 + kkv * 32 + g * 8) ^ ((l16 & 7) << 3)));
      bf16x8 vf[4];
#pragma unroll
      for (int nd = 0; nd < 4; nd++)
        vf[nd] = *(const bf16x8*)(vt + (size_t)(nd * 16 + l16) * 1024 + kv0 + kkv * 32 + g * 8);
#pragma unroll
      for (int nd = 0; nd < 4; nd++)
        oacc[nd] = __builtin_amdgcn_mfma_f32_16x16x32_bf16(pf, vf[nd], oacc[nd], 0, 0, 0);
    }
  }

  // epilogue: O rows q = q0 + w*16 + g*4 + r, cols d = nd*16 + l16
#pragma unroll
  for (int nd = 0; nd < 4; nd++) {
#pragma unroll
    for (int r = 0; r < 4; r++) {
      const int q = q0 + w * 16 + g * 4 + r;
      aout[(size_t)(b * 1024 + q) * 768 + h * 64 + nd * 16 + l16] = (bf16)oacc[nd][r];
    }
  }
}

// ---------------- blend: xa = 0.5*xa + 0.5*xb ----------------
__global__ __launch_bounds__(256) void blend_k(float* __restrict__ xa,
                                               const float* __restrict__ xb, int n4) {
  const int i = blockIdx.x * 256 + threadIdx.x;
  if (i < n4) {
    float4 a = ((float4*)xa)[i];
    const float4 c = ((const float4*)xb)[i];
    a.x = 0.5f * (a.x + c.x); a.y = 0.5f * (a.y + c.y);
    a.z = 0.5f * (a.z + c.z); a.w = 0.5f * (a.w + c.w);
    ((float4*)xa)[i] = a;
  }
}

// ---------------- host ----------------
extern "C" void kernel_launch(void* const* d_in, const int* in_sizes, int n_in,
                              void* d_out, int out_size, void* d_ws, size_t ws_size,
                              hipStream_t stream) {
  (void)in_sizes; (void)n_in; (void)out_size; (void)ws_size;
  const float* x = (const float*)d_in[0];
#define IN(d, i) ((const float*)d_in[1 + (d) * 12 + (i)])
  float* outF = (float*)d_out;
  float* attnp[2] = {outF + 3145728, outF + 3145728 + 50331648};

  char* p = (char*)d_ws;
  auto alloc = [&](size_t bytes) { void* r = p; p += bytes; return r; };
  bf16 *qkv_wt[2], *proj_wt[2], *w1t[2], *w2t[2];
  for (int d = 0; d < 2; d++) {
    qkv_wt[d]  = (bf16*)alloc((size_t)2304 * 768 * 2);
    proj_wt[d] = (bf16*)alloc((size_t)768 * 768 * 2);
    w1t[d]     = (bf16*)alloc((size_t)3072 * 768 * 2);
    w2t[d]     = (bf16*)alloc((size_t)768 * 3072 * 2);
  }
  bf16*  hbuf = (bf16*)alloc((size_t)4096 * 768 * 2);
  bf16*  qkvb = (bf16*)alloc((size_t)4096 * 2304 * 2);
  bf16*  vT   = (bf16*)alloc((size_t)48 * 64 * 1024 * 2);
  bf16*  aout = (bf16*)alloc((size_t)4096 * 768 * 2);
  bf16*  hid  = (bf16*)alloc((size_t)4096 * 3072 * 2);
  float* xa   = (float*)alloc((size_t)4096 * 768 * 4);
  float* xb   = (float*)alloc((size_t)4096 * 768 * 4);

  for (int d = 0; d < 2; d++) {
    transpose_cast_k<<<dim3(72, 24), 256, 0, stream>>>(IN(d, 0), qkv_wt[d], 768, 2304);
    transpose_cast_k<<<dim3(24, 24), 256, 0, stream>>>(IN(d, 2), proj_wt[d], 768, 768);
    transpose_cast_k<<<dim3(96, 24), 256, 0, stream>>>(IN(d, 8), w1t[d], 768, 3072);
    transpose_cast_k<<<dim3(24, 96), 256, 0, stream>>>(IN(d, 10), w2t[d], 3072, 768);
  }

  auto attention = [&](int d, const float* xin, float* xout) {
    ln_k<<<1024, 256, 0, stream>>>(xin, IN(d, 4), IN(d, 5), hbuf);
    gemm_bt_k<0><<<dim3(18, 32), 256, 0, stream>>>(hbuf, 768, qkv_wt[d], 768, IN(d, 1),
                                                   nullptr, qkvb, 2304, 768);
    vtrans_k<<<dim3(32, 2, 48), 256, 0, stream>>>(qkvb, vT);
    fattn_k<<<768, 256, 0, stream>>>(qkvb, vT, attnp[d], aout);
    gemm_bt_k<2><<<dim3(6, 32), 256, 0, stream>>>(aout, 768, proj_wt[d], 768, IN(d, 3),
                                                  xin, xout, 768, 768);
  };

  // layer 0 attention: xa = x + attn0(LN1_0(x))
  attention(0, x, xa);
  // layer 1 attention: xb = xa + attn1(LN1_1(xa))
  attention(1, xa, xb);
  // layer 1 MLP: xb <- xb + mlp1(LN2_1(xb))   (x_sub)
  ln_k<<<1024, 256, 0, stream>>>(xb, IN(1, 6), IN(1, 7), hbuf);
  gemm_bt_k<1><<<dim3(24, 32), 256, 0, stream>>>(hbuf, 768, w1t[1], 768, IN(1, 9),
                                                 nullptr, hid, 3072, 768);
  gemm_bt_k<2><<<dim3(6, 32), 256, 0, stream>>>(hid, 3072, w2t[1], 3072, IN(1, 11),
                                                xb, xb, 768, 3072);
  // blend: xa <- 0.5*xa + 0.5*xb
  blend_k<<<3072, 256, 0, stream>>>(xa, xb, 786432);
  // layer 0 MLP: out = xa + mlp0(LN2_0(xa))
  ln_k<<<1024, 256, 0, stream>>>(xa, IN(0, 6), IN(0, 7), hbuf);
  gemm_bt_k<1><<<dim3(24, 32), 256, 0, stream>>>(hbuf, 768, w1t[0], 768, IN(0, 9),
                                                 nullptr, hid, 3072, 768);
  gemm_bt_k<2><<<dim3(6, 32), 256, 0, stream>>>(hid, 3072, w2t[0], 3072, IN(0, 11),
                                                xa, outF, 768, 3072);
#undef IN
}

// Round 5
// 564.775 us; speedup vs baseline: 1.4348x; 1.0510x over previous
//
#include <hip/hip_runtime.h>
#include <hip/hip_bf16.h>
#include <stdint.h>

typedef __bf16 bf16;
typedef __bf16 bf16x8 __attribute__((ext_vector_type(8)));
typedef __bf16 bf16x4 __attribute__((ext_vector_type(4)));
typedef float  f32x4  __attribute__((ext_vector_type(4)));

#define GLOAD16(gsrc, ldst)                                                        \
  __builtin_amdgcn_global_load_lds(                                               \
      (const __attribute__((address_space(1))) void*)(gsrc),                      \
      (__attribute__((address_space(3))) void*)(ldst), 16, 0, 0)

__device__ __forceinline__ float gelu_f(float v) {
  return 0.5f * v * (1.0f + erff(v * 0.70710678118654752f));
}

// ---- batched transpose+cast: all 8 weights, W[K,N] f32 -> Wt[N,K] bf16 ----
// per layer 6912 tiles: [0,1728) qkv(768,2304) [1728,2304) proj(768,768)
// [2304,4608) w1(768,3072) [4608,6912) w2(3072,768)
__global__ __launch_bounds__(256) void transpose_all_k(
    const float* __restrict__ qw0, bf16* __restrict__ qt0,
    const float* __restrict__ pw0, bf16* __restrict__ pt0,
    const float* __restrict__ w10, bf16* __restrict__ t10,
    const float* __restrict__ w20, bf16* __restrict__ t20,
    const float* __restrict__ qw1, bf16* __restrict__ qt1,
    const float* __restrict__ pw1, bf16* __restrict__ pt1,
    const float* __restrict__ w11, bf16* __restrict__ t11,
    const float* __restrict__ w21, bf16* __restrict__ t21) {
  __shared__ float tile[32][33];
  int i = blockIdx.x;
  const int d = (i >= 6912) ? 1 : 0;
  i -= d * 6912;
  const float* W; bf16* Wt; int K, N, nt;
  if (i < 1728)      { W = d ? qw1 : qw0; Wt = d ? qt1 : qt0; K = 768;  N = 2304; nt = 72; }
  else if (i < 2304) { i -= 1728; W = d ? pw1 : pw0; Wt = d ? pt1 : pt0; K = 768; N = 768; nt = 24; }
  else if (i < 4608) { i -= 2304; W = d ? w11 : w10; Wt = d ? t11 : t10; K = 768; N = 3072; nt = 96; }
  else               { i -= 4608; W = d ? w21 : w20; Wt = d ? t21 : t20; K = 3072; N = 768; nt = 24; }
  const int n0 = (i % nt) * 32, k0 = (i / nt) * 32;
  const int tx = threadIdx.x & 31, ty = threadIdx.x >> 5;
#pragma unroll
  for (int j = ty; j < 32; j += 8)
    tile[j][tx] = W[(size_t)(k0 + j) * N + n0 + tx];
  __syncthreads();
#pragma unroll
  for (int j = ty; j < 32; j += 8)
    Wt[(size_t)(n0 + j) * K + k0 + tx] = (bf16)tile[tx][j];
}

// ---------------- LayerNorm: f32 [T,768] -> bf16 [T,768] ----------------
__global__ __launch_bounds__(256) void ln_k(
    const float* __restrict__ x, const float* __restrict__ g,
    const float* __restrict__ b, bf16* __restrict__ out) {
  const int token = blockIdx.x * 4 + (threadIdx.x >> 6);
  const int lane  = threadIdx.x & 63;
  const float4* xp = (const float4*)(x + (size_t)token * 768);
  float4 v[3];
  float s = 0.f, ss = 0.f;
#pragma unroll
  for (int j = 0; j < 3; j++) {
    v[j] = xp[lane + j * 64];
    s  += v[j].x + v[j].y + v[j].z + v[j].w;
    ss += v[j].x * v[j].x + v[j].y * v[j].y + v[j].z * v[j].z + v[j].w * v[j].w;
  }
#pragma unroll
  for (int o = 32; o > 0; o >>= 1) { s += __shfl_xor(s, o); ss += __shfl_xor(ss, o); }
  const float mu  = s * (1.f / 768.f);
  const float var = ss * (1.f / 768.f) - mu * mu;
  const float r   = rsqrtf(var + 1e-5f);
#pragma unroll
  for (int j = 0; j < 3; j++) {
    const int c0 = (lane + j * 64) * 4;
    bf16x4 o4;
    o4[0] = (bf16)((v[j].x - mu) * r * g[c0 + 0] + b[c0 + 0]);
    o4[1] = (bf16)((v[j].y - mu) * r * g[c0 + 1] + b[c0 + 1]);
    o4[2] = (bf16)((v[j].z - mu) * r * g[c0 + 2] + b[c0 + 2]);
    o4[3] = (bf16)((v[j].w - mu) * r * g[c0 + 3] + b[c0 + 3]);
    *(bf16x4*)(out + (size_t)token * 768 + c0) = o4;
  }
}

// ---------------- generic GEMM: C[M,N] = A[M,K] @ Bt[N,K]^T ----------------
// EPI 0: bf16 = acc+bias   EPI 1: bf16 = gelu(acc+bias)
// EPI 2: f32  = acc+bias+res   EPI 3: f32 = 0.5*(acc+bias+res+res2)
template <int EPI>
__global__ __launch_bounds__(256) void gemm_bt_k(
    const bf16* __restrict__ A, int lda,
    const bf16* __restrict__ Bt, int ldb,
    const float* __restrict__ bias,
    const float* __restrict__ res,
    const float* __restrict__ res2,
    void* __restrict__ outp, int ldc, int K) {
  __shared__ __align__(16) bf16 As[128 * 64];
  __shared__ __align__(16) bf16 Bs[128 * 64];
  const int t = threadIdx.x, wave = t >> 6, lane = t & 63;
  const int row0 = blockIdx.y * 128, col0 = blockIdx.x * 128;
  const int wm = wave >> 1, wn = wave & 1;
  const int sr = t >> 3, sc = (t & 7) * 8;

  f32x4 acc[4][4];
#pragma unroll
  for (int m = 0; m < 4; m++)
#pragma unroll
    for (int n = 0; n < 4; n++) acc[m][n] = f32x4{0.f, 0.f, 0.f, 0.f};

  const bf16* a_src = A + (size_t)(row0 + sr) * lda + sc;
  const bf16* b_src = Bt + (size_t)(col0 + sr) * ldb + sc;
  bf16* a_dst = As + wave * 512;
  bf16* b_dst = Bs + wave * 512;

  for (int k0 = 0; k0 < K; k0 += 64) {
#pragma unroll
    for (int i = 0; i < 4; i++) {
      GLOAD16(a_src + (size_t)i * 32 * lda + k0, a_dst + i * 2048);
      GLOAD16(b_src + (size_t)i * 32 * ldb + k0, b_dst + i * 2048);
    }
    __syncthreads();
#pragma unroll
    for (int kk = 0; kk < 2; kk++) {
      const int ko = kk * 32 + (lane >> 4) * 8;
      bf16x8 af[4], bfr[4];
#pragma unroll
      for (int m = 0; m < 4; m++)
        af[m] = *(const bf16x8*)(As + (wm * 64 + m * 16 + (lane & 15)) * 64 + ko);
#pragma unroll
      for (int n = 0; n < 4; n++)
        bfr[n] = *(const bf16x8*)(Bs + (wn * 64 + n * 16 + (lane & 15)) * 64 + ko);
#pragma unroll
      for (int m = 0; m < 4; m++)
#pragma unroll
        for (int n = 0; n < 4; n++)
          acc[m][n] = __builtin_amdgcn_mfma_f32_16x16x32_bf16(af[m], bfr[n], acc[m][n], 0, 0, 0);
    }
    __syncthreads();
  }

  const int rbase = row0 + wm * 64 + (lane >> 4) * 4;
  const int cbase = col0 + wn * 64 + (lane & 15);
#pragma unroll
  for (int n = 0; n < 4; n++) {
    const int c = cbase + n * 16;
    const float bv = bias[c];
#pragma unroll
    for (int m = 0; m < 4; m++) {
#pragma unroll
      for (int r = 0; r < 4; r++) {
        const int rr = rbase + m * 16 + r;
        const float vacc = acc[m][n][r] + bv;
        if constexpr (EPI == 0) {
          ((bf16*)outp)[(size_t)rr * ldc + c] = (bf16)vacc;
        } else if constexpr (EPI == 1) {
          ((bf16*)outp)[(size_t)rr * ldc + c] = (bf16)gelu_f(vacc);
        } else if constexpr (EPI == 2) {
          ((float*)outp)[(size_t)rr * ldc + c] = vacc + res[(size_t)rr * ldc + c];
        } else {
          ((float*)outp)[(size_t)rr * ldc + c] =
              0.5f * (vacc + res[(size_t)rr * ldc + c] + res2[(size_t)rr * ldc + c]);
        }
      }
    }
  }
}

// ---------------- V transpose: vT[bh][d][q] <- qkv[b*1024+q][1536+h*64+d] ----------------
__global__ __launch_bounds__(256) void vtrans_k(const bf16* __restrict__ qkv,
                                                bf16* __restrict__ vT) {
  __shared__ bf16 tile[32][33];
  const int bh = blockIdx.z, b = bh / 12, h = bh % 12;
  const int q0 = blockIdx.x * 32, d0 = blockIdx.y * 32;
  const int tx = threadIdx.x & 31, ty = threadIdx.x >> 5;
  const bf16* src = qkv + (size_t)b * 1024 * 2304 + 1536 + h * 64;
#pragma unroll
  for (int i = ty; i < 32; i += 8)
    tile[i][tx] = src[(size_t)(q0 + i) * 2304 + d0 + tx];
  __syncthreads();
  bf16* dst = vT + (size_t)bh * 65536;
#pragma unroll
  for (int i = ty; i < 32; i += 8)
    dst[(size_t)(d0 + i) * 1024 + q0 + tx] = tile[tx][i];
}

// ---------------- fused attention: S^T via mfma(K,Q), 2-pass softmax, P write, PV ----
__global__ __launch_bounds__(256) void fattn_k(const bf16* __restrict__ qkv,
                                               const bf16* __restrict__ vT,
                                               float* __restrict__ attn,
                                               bf16* __restrict__ aout) {
  __shared__ __align__(16) bf16 Ks[128 * 64];     // K tile, source-swizzled
  __shared__ __align__(16) bf16 Ps[4 * 16 * 128]; // per-wave P tile, swizzled

  const float S2 = 0.18033688011112042f;  // 0.125 * log2(e)

  const int bid = blockIdx.x;
  const int xcd = bid & 7, within = bid >> 3;
  const int bh = xcd * 6 + (within >> 4);
  const int qb = within & 15;
  const int b = bh / 12, h = bh % 12;

  const int t = threadIdx.x, w = t >> 6, lane = t & 63;
  const int g = lane >> 4, l16 = lane & 15;
  const int q0 = qb * 64;

  const bf16* qbp = qkv + (size_t)b * 1024 * 2304 + h * 64;
  const bf16* kbp = qbp + 768;
  const bf16* vt = vT + (size_t)bh * 65536;
  float* Pout = attn + (size_t)bh * 1048576;
  bf16* Pw = Ps + w * 2048;

  bf16x8 qf[2];
#pragma unroll
  for (int kk = 0; kk < 2; kk++)
    qf[kk] = *(const bf16x8*)(qbp + (size_t)(q0 + w * 16 + l16) * 2304 + kk * 32 + g * 8);

  const int kvr = t >> 3, sl = t & 7;

  float m_run = -3.0e38f, l_run = 0.f;

  // ---------------- pass 1: online (max, sum) ----------------
  for (int kv0 = 0; kv0 < 1024; kv0 += 128) {
#pragma unroll
    for (int i = 0; i < 4; i++) {
      const int kvl = i * 32 + kvr;
      GLOAD16(kbp + (size_t)(kv0 + kvl) * 2304 + (sl ^ (kvl & 7)) * 8,
              Ks + i * 2048 + t * 8);
    }
    __syncthreads();
    f32x4 st[8];
#pragma unroll
    for (int mk = 0; mk < 8; mk++) st[mk] = f32x4{0.f, 0.f, 0.f, 0.f};
    __builtin_amdgcn_s_setprio(1);
#pragma unroll
    for (int kk = 0; kk < 2; kk++) {
#pragma unroll
      for (int mk = 0; mk < 8; mk++) {
        const int kv = mk * 16 + l16;
        const bf16x8 kf = *(const bf16x8*)(Ks + ((kv * 64 + kk * 32 + g * 8) ^ ((kv & 7) << 3)));
        st[mk] = __builtin_amdgcn_mfma_f32_16x16x32_bf16(kf, qf[kk], st[mk], 0, 0, 0);
      }
    }
    __builtin_amdgcn_s_setprio(0);
    __syncthreads();
    float tm = -3.0e38f;
#pragma unroll
    for (int mk = 0; mk < 8; mk++)
#pragma unroll
      for (int r = 0; r < 4; r++) tm = fmaxf(tm, st[mk][r]);
    tm = fmaxf(tm, __shfl_xor(tm, 16));
    tm = fmaxf(tm, __shfl_xor(tm, 32));
    const float mn = fmaxf(m_run, tm);
    const float ms2 = mn * S2;
    float sum = 0.f;
#pragma unroll
    for (int mk = 0; mk < 8; mk++)
#pragma unroll
      for (int r = 0; r < 4; r++) sum += exp2f(fmaf(st[mk][r], S2, -ms2));
    sum += __shfl_xor(sum, 16);
    sum += __shfl_xor(sum, 32);
    l_run = l_run * exp2f((m_run - mn) * S2) + sum;
    m_run = mn;
  }

  const float msc2 = m_run * S2;
  const float invl = 1.f / l_run;

  f32x4 oacc[4];
#pragma unroll
  for (int nd = 0; nd < 4; nd++) oacc[nd] = f32x4{0.f, 0.f, 0.f, 0.f};

  // ---------------- pass 2: recompute S, write P, PV ----------------
  for (int kv0 = 0; kv0 < 1024; kv0 += 128) {
#pragma unroll
    for (int i = 0; i < 4; i++) {
      const int kvl = i * 32 + kvr;
      GLOAD16(kbp + (size_t)(kv0 + kvl) * 2304 + (sl ^ (kvl & 7)) * 8,
              Ks + i * 2048 + t * 8);
    }
    __syncthreads();
    f32x4 st[8];
#pragma unroll
    for (int mk = 0; mk < 8; mk++) st[mk] = f32x4{0.f, 0.f, 0.f, 0.f};
    __builtin_amdgcn_s_setprio(1);
#pragma unroll
    for (int kk = 0; kk < 2; kk++) {
#pragma unroll
      for (int mk = 0; mk < 8; mk++) {
        const int kv = mk * 16 + l16;
        const bf16x8 kf = *(const bf16x8*)(Ks + ((kv * 64 + kk * 32 + g * 8) ^ ((kv & 7) << 3)));
        st[mk] = __builtin_amdgcn_mfma_f32_16x16x32_bf16(kf, qf[kk], st[mk], 0, 0, 0);
      }
    }
    __builtin_amdgcn_s_setprio(0);
    __syncthreads();

    const int q = q0 + w * 16 + l16;
#pragma unroll
    for (int mk = 0; mk < 8; mk++) {
      f32x4 pv;
      pv[0] = exp2f(fmaf(st[mk][0], S2, -msc2)) * invl;
      pv[1] = exp2f(fmaf(st[mk][1], S2, -msc2)) * invl;
      pv[2] = exp2f(fmaf(st[mk][2], S2, -msc2)) * invl;
      pv[3] = exp2f(fmaf(st[mk][3], S2, -msc2)) * invl;
      __builtin_nontemporal_store(pv, (f32x4*)(Pout + (size_t)q * 1024 + kv0 + mk * 16 + g * 4));
      bf16x4 pb;
      pb[0] = (bf16)pv[0]; pb[1] = (bf16)pv[1]; pb[2] = (bf16)pv[2]; pb[3] = (bf16)pv[3];
      *(bf16x4*)(Pw + ((l16 * 128 + mk * 16 + g * 4) ^ ((l16 & 7) << 3))) = pb;
    }

#pragma unroll
    for (int kkv = 0; kkv < 4; kkv++) {
      const bf16x8 pf = *(const bf16x8*)(Pw + ((l16 * 128 + kkv * 32 + g * 8) ^ ((l16 & 7) << 3)));
      bf16x8 vf[4];
#pragma unroll
      for (int nd = 0; nd < 4; nd++)
        vf[nd] = *(const bf16x8*)(vt + (size_t)(nd * 16 + l16) * 1024 + kv0 + kkv * 32 + g * 8);
      __builtin_amdgcn_s_setprio(1);
#pragma unroll
      for (int nd = 0; nd < 4; nd++)
        oacc[nd] = __builtin_amdgcn_mfma_f32_16x16x32_bf16(pf, vf[nd], oacc[nd], 0, 0, 0);
      __builtin_amdgcn_s_setprio(0);
    }
  }

#pragma unroll
  for (int nd = 0; nd < 4; nd++) {
#pragma unroll
    for (int r = 0; r < 4; r++) {
      const int q = q0 + w * 16 + g * 4 + r;
      aout[(size_t)(b * 1024 + q) * 768 + h * 64 + nd * 16 + l16] = (bf16)oacc[nd][r];
    }
  }
}

// ---------------- host ----------------
extern "C" void kernel_launch(void* const* d_in, const int* in_sizes, int n_in,
                              void* d_out, int out_size, void* d_ws, size_t ws_size,
                              hipStream_t stream) {
  (void)in_sizes; (void)n_in; (void)out_size; (void)ws_size;
  const float* x = (const float*)d_in[0];
#define IN(d, i) ((const float*)d_in[1 + (d) * 12 + (i)])
  float* outF = (float*)d_out;
  float* attnp[2] = {outF + 3145728, outF + 3145728 + 50331648};

  char* p = (char*)d_ws;
  auto alloc = [&](size_t bytes) { void* r = p; p += bytes; return r; };
  bf16 *qkv_wt[2], *proj_wt[2], *w1t[2], *w2t[2];
  for (int d = 0; d < 2; d++) {
    qkv_wt[d]  = (bf16*)alloc((size_t)2304 * 768 * 2);
    proj_wt[d] = (bf16*)alloc((size_t)768 * 768 * 2);
    w1t[d]     = (bf16*)alloc((size_t)3072 * 768 * 2);
    w2t[d]     = (bf16*)alloc((size_t)768 * 3072 * 2);
  }
  bf16*  hbuf = (bf16*)alloc((size_t)4096 * 768 * 2);
  bf16*  qkvb = (bf16*)alloc((size_t)4096 * 2304 * 2);
  bf16*  vT   = (bf16*)alloc((size_t)48 * 64 * 1024 * 2);
  bf16*  aout = (bf16*)alloc((size_t)4096 * 768 * 2);
  bf16*  hid  = (bf16*)alloc((size_t)4096 * 3072 * 2);
  float* xa   = (float*)alloc((size_t)4096 * 768 * 4);
  float* xb   = (float*)alloc((size_t)4096 * 768 * 4);

  transpose_all_k<<<13824, 256, 0, stream>>>(
      IN(0, 0), qkv_wt[0], IN(0, 2), proj_wt[0], IN(0, 8), w1t[0], IN(0, 10), w2t[0],
      IN(1, 0), qkv_wt[1], IN(1, 2), proj_wt[1], IN(1, 8), w1t[1], IN(1, 10), w2t[1]);

  auto attention = [&](int d, const float* xin, float* xout) {
    ln_k<<<1024, 256, 0, stream>>>(xin, IN(d, 4), IN(d, 5), hbuf);
    gemm_bt_k<0><<<dim3(18, 32), 256, 0, stream>>>(hbuf, 768, qkv_wt[d], 768, IN(d, 1),
                                                   nullptr, nullptr, qkvb, 2304, 768);
    vtrans_k<<<dim3(32, 2, 48), 256, 0, stream>>>(qkvb, vT);
    fattn_k<<<768, 256, 0, stream>>>(qkvb, vT, attnp[d], aout);
    gemm_bt_k<2><<<dim3(6, 32), 256, 0, stream>>>(aout, 768, proj_wt[d], 768, IN(d, 3),
                                                  xin, nullptr, xout, 768, 768);
  };

  // layer 0 attention: xa = x + attn0(LN1_0(x))
  attention(0, x, xa);
  // layer 1 attention: xb = xa + attn1(LN1_1(xa))
  attention(1, xa, xb);
  // layer 1 MLP + blend fold: xa <- 0.5*(xa + xb + mlp1(LN2_1(xb)))
  ln_k<<<1024, 256, 0, stream>>>(xb, IN(1, 6), IN(1, 7), hbuf);
  gemm_bt_k<1><<<dim3(24, 32), 256, 0, stream>>>(hbuf, 768, w1t[1], 768, IN(1, 9),
                                                 nullptr, nullptr, hid, 3072, 768);
  gemm_bt_k<3><<<dim3(6, 32), 256, 0, stream>>>(hid, 3072, w2t[1], 3072, IN(1, 11),
                                                xb, xa, xa, 768, 3072);
  // layer 0 MLP: out = xa + mlp0(LN2_0(xa))
  ln_k<<<1024, 256, 0, stream>>>(xa, IN(0, 6), IN(0, 7), hbuf);
  gemm_bt_k<1><<<dim3(24, 32), 256, 0, stream>>>(hbuf, 768, w1t[0], 768, IN(0, 9),
                                                 nullptr, nullptr, hid, 3072, 768);
  gemm_bt_k<2><<<dim3(6, 32), 256, 0, stream>>>(hid, 3072, w2t[0], 3072, IN(0, 11),
                                                xa, nullptr, outF, 768, 3072);
#undef IN
}